// Round 16
// baseline (99.557 us; speedup 1.0000x reference)
//
#include <hip/hip_runtime.h>

#define N_ANGLES 180
#define IMG 256
#define SPAD 363            // ceil(sqrt(2)*256)
#define PB 53               // pad_before = (363-256)//2
#define BATCH 2
#define TOTAL (BATCH * N_ANGLES * SPAD)   // 130680 output elements
#define GEOM (N_ANGLES * SPAD)            // 65340 geometry outputs (both batches)
#define RSPLIT 8                          // r-residue classes per geometry output
#define NBLK2 ((GEOM + 31) / 32)          // 2042 blocks (32 geom outputs each)
#define NPAD 2048                         // padded grid for the XCD swizzle

// ---- batch-interleaved quad table:
//   entry(v, y, x) = [ Q_b0(y,x) | Q_b1(y,x) ]  (2x float4 = 32B)
//   Q_b(y,x) = (v(y,x), v(y,x+1), v(y+1,x), v(y+1,x+1)), 0 outside image.
// Both batches share geometry -> the b1 load rides the b0 load's cache lines,
// halving L2 line traffic (r15 counters: L2-BW bound at ~38 us).
#define QB 6
#define QDIM (IMG + 2 * QB)              // 268
#define QELEMS (QDIM * QDIM)             // 71824
#define COFF ((QB - PB) * (QDIM + 1))    // folds (+QB, -PB) into one constant

__global__ __launch_bounds__(256) void prep_quad2(const float* __restrict__ img,
                                                  float4* __restrict__ quad) {
    const int n = blockIdx.x * 256 + threadIdx.x;   // entry id
    if (n >= 2 * QELEMS) return;
    const int xq = n % QDIM;
    const int yq = (n / QDIM) % QDIM;
    const int v  = n / QELEMS;           // 0 = normal, 1 = transposed
    const int x = xq - QB, y = yq - QB;
#pragma unroll
    for (int b = 0; b < BATCH; ++b) {
        const float* ib = img + b * (IMG * IMG);
        auto val = [&](int yy, int xx) -> float {
            if ((unsigned)yy >= (unsigned)IMG || (unsigned)xx >= (unsigned)IMG) return 0.0f;
            return v ? ib[xx * IMG + yy] : ib[yy * IMG + xx];
        };
        float4 q;
        q.x = val(y, x);     q.y = val(y, x + 1);
        q.z = val(y + 1, x); q.w = val(y + 1, x + 1);
        quad[n * 2 + b] = q;
    }
}

// one geometry sample -> bilinear for BOTH batches (A0, A1 accumulators)
#define SAMP2(r, A0, A1)                                                       \
    {                                                                          \
        const float rf = (float)(r);                                           \
        const float ix = fmaf(rf, stepA, v0A);                                 \
        const float iy = fmaf(rf, stepB, v0B);                                 \
        const float wx = ix - floorf(ix);       /* v_fract (ix > 0 always) */  \
        const float wy = iy - floorf(iy);                                      \
        const int   xi = (int)ix;                                              \
        const int   yi = (int)iy;                                              \
        const float4* e = qt + 2 * (yi * QDIM + xi) + 2 * COFF;                \
        const float4 q0 = e[0];                                                \
        const float4 q1 = e[1];                                                \
        const float omwx = 1.0f - wx;                                          \
        const float omwy = 1.0f - wy;                                          \
        const float t0 = fmaf(q0.y, wx, q0.x * omwx);                          \
        const float b0 = fmaf(q0.w, wx, q0.z * omwx);                          \
        A0 = fmaf(b0, wy, fmaf(t0, omwy, A0));                                 \
        const float t1 = fmaf(q1.y, wx, q1.x * omwx);                          \
        const float b1 = fmaf(q1.w, wx, q1.z * omwx);                          \
        A1 = fmaf(b1, wy, fmaf(t1, omwy, A1));                                 \
    }

__global__ __launch_bounds__(256) void radon_quad2(const float4* __restrict__ quad,
                                                   float* __restrict__ out) {
    // XCD-affine swizzle: each XCD works one contiguous chunk of the
    // orientation-grouped work list.
    const int L  = blockIdx.x;                       // 0..2047
    const int ob = (L & 7) * (NPAD / 8) + (L >> 3);  // bijection on [0,2048)
    if (ob >= NBLK2) return;
    const int o2 = ob * 32 + (threadIdx.x >> 3);     // geometry output
    const int p  = threadIdx.x & 7;                  // r-residue class mod 8
    if (o2 >= GEOM) return;                          // octet-aligned exit

    // orientation-grouped ordering: o2 = j*SPAD + t, where
    //   j <  46 -> a = j        (normal,     theta in [0,45])
    //   j <  91 -> a = j + 89   (normal,     theta in [135,179])
    //   j >= 91 -> a = j - 45   (transposed, theta in [46,134])
    const int t = o2 % SPAD;
    const int j = o2 / SPAD;
    const int a = j + (j < 46 ? 0 : (j < 91 ? 89 : -45));
    const bool useT = (j >= 91);   // layout choice only; both layouts exact

    const float theta = (float)a * 0.017453292519943295f;  // float32(pi/180)
    float s, c;
    sincosf(theta, &s, &c);

    const float d  = 2.0f / 362.0f;
    const float lt = fmaf((float)t, d, -1.0f);      // x = lin[t]
    const float ct  = c * lt;                       // cos*x
    const float mst = -s * lt;                      // -sin*x

    // steep angles: transposed table with (x,y)/(wx,wy) swapped — bilinear is
    // exactly symmetric; caps gather slope at 0.707.
    const float sA = useT ? c   : s;     // ix(r) = (sA*lr + cA + 1) * 181
    const float cA = useT ? mst : ct;
    const float sB = useT ? s   : c;     // iy(r) = (sB*lr + cB + 1) * 181
    const float cB = useT ? ct  : mst;
    const float4* __restrict__ qt = quad + (useT ? 2 * QELEMS : 0);

    // exact linear model driving BOTH the clip and the loop (<= ~3e-5 px dev)
    const float fA = sA * 181.0f, gA = (cA + 1.0f) * 181.0f;
    const float fB = sB * 181.0f, gB = (cB + 1.0f) * 181.0f;
    const float v0A = fmaf(fA, -1.0f, gA), stepA = fA * d;
    const float v0B = fmaf(fB, -1.0f, gB), stepB = fB * d;

    // intersect { r : v0 + r*step in [lo,hi] }
    float rlo = 0.0f, rhi = 362.0f;
    {
        const float lo = 51.0f, hi = 310.0f;   // exact nonzero range is [52,309)
        if (fabsf(stepA) < 1e-5f) {
            if (v0A < lo || v0A > hi) { rlo = 363.0f; rhi = -1.0f; }
        } else {
            const float r0 = (lo - v0A) / stepA;
            const float r1 = (hi - v0A) / stepA;
            rlo = fmaxf(rlo, fminf(r0, r1));
            rhi = fminf(rhi, fmaxf(r0, r1));
        }
        if (fabsf(stepB) < 1e-5f) {
            if (v0B < lo || v0B > hi) { rlo = 363.0f; rhi = -1.0f; }
        } else {
            const float r0 = (lo - v0B) / stepB;
            const float r1 = (hi - v0B) / stepB;
            rlo = fmaxf(rlo, fminf(r0, r1));
            rhi = fminf(rhi, fmaxf(r0, r1));
        }
    }
    const int rmin = max(0,   (int)floorf(rlo));
    const int rmax = min(362, (int)ceilf(rhi));
    // executed ix in [49.99, 311.01] -> table idx stays inside the QB=6 border.

    // lane p covers r ≡ p (mod 8); dual accumulator pairs at stride 16 keep
    // 4 loads in flight (L2-BW bound, so deeper MLP is not the lever).
    float a00 = 0.0f, a01 = 0.0f;   // batch 0
    float a10 = 0.0f, a11 = 0.0f;   // batch 1
    int r = rmin + ((p - rmin) & 7);
    for (; r + 8 <= rmax; r += 16) {
        SAMP2(r,     a00, a10);
        SAMP2(r + 8, a01, a11);
    }
    if (r <= rmax) SAMP2(r, a00, a10);
    float accB0 = a00 + a01;
    float accB1 = a10 + a11;

    // reduce the 8 r-residue partials (lanes o2*8+0..7 form an aligned octet)
    accB0 += __shfl_xor(accB0, 1);
    accB0 += __shfl_xor(accB0, 2);
    accB0 += __shfl_xor(accB0, 4);
    accB1 += __shfl_xor(accB1, 1);
    accB1 += __shfl_xor(accB1, 2);
    accB1 += __shfl_xor(accB1, 4);

    if (p == 0) {
        // out shape (B,1,SPAD,N_ANGLES): out[b][0][t][a]
        const int base = t * N_ANGLES + a;
        out[base] = accB0;
        out[base + SPAD * N_ANGLES] = accB1;
    }
}

// ---------------- fallback path (validated round-4 kernel) ----------------

__global__ __launch_bounds__(256) void transpose_kernel(const float* __restrict__ img,
                                                        float* __restrict__ imgT) {
    __shared__ float tile[32][33];
    const int b  = blockIdx.z;
    const int tx = blockIdx.x * 32;
    const int ty = blockIdx.y * 32;
    const int lx = threadIdx.x & 31;
    const int l8 = threadIdx.x >> 5;
    const float* ib = img  + b * IMG * IMG;
    float*       ob = imgT + b * IMG * IMG;
#pragma unroll
    for (int i = 0; i < 4; ++i) {
        const int ly = l8 + i * 8;
        tile[ly][lx] = ib[(ty + ly) * IMG + tx + lx];
    }
    __syncthreads();
#pragma unroll
    for (int i = 0; i < 4; ++i) {
        const int ly = l8 + i * 8;
        ob[(tx + ly) * IMG + ty + lx] = tile[lx][ly];
    }
}

#define SAMPLE(r, CHECKED)                                                     \
    {                                                                          \
        const float lr  = fmaf((float)(r), d, -1.0f);                          \
        const float ix  = fmaf(fA, lr, gA);                                    \
        const float iy  = fmaf(fB, lr, gB);                                    \
        const float wx  = ix - floorf(ix);                                     \
        const float wy  = iy - floorf(iy);                                     \
        const int   xi  = (int)ix;                                             \
        const int   yi  = (int)iy;                                             \
        float v00, v01, v10, v11;                                              \
        if (CHECKED) {                                                         \
            const int xA = xi - PB, yA = yi - PB;                              \
            const bool vx0 = (unsigned)xA       < (unsigned)IMG;               \
            const bool vx1 = (unsigned)(xA + 1) < (unsigned)IMG;               \
            const bool vy0 = (unsigned)yA       < (unsigned)IMG;               \
            const bool vy1 = (unsigned)(yA + 1) < (unsigned)IMG;               \
            const float* rp = base + yA * IMG + xA;                            \
            v00 = (vx0 && vy0) ? rp[0]       : 0.0f;                           \
            v01 = (vx1 && vy0) ? rp[1]       : 0.0f;                           \
            v10 = (vx0 && vy1) ? rp[IMG]     : 0.0f;                           \
            v11 = (vx1 && vy1) ? rp[IMG + 1] : 0.0f;                           \
        } else {                                                               \
            const float* rp = base + (yi * IMG + xi - (PB * IMG + PB));        \
            v00 = rp[0]; v01 = rp[1]; v10 = rp[IMG]; v11 = rp[IMG + 1];        \
        }                                                                      \
        const float omwx = 1.0f - wx;                                          \
        const float omwy = 1.0f - wy;                                          \
        const float top  = fmaf(v01, wx, v00 * omwx);                          \
        const float bot  = fmaf(v11, wx, v10 * omwx);                          \
        acc = fmaf(bot, wy, fmaf(top, omwy, acc));                             \
    }

template <bool HAVE_T>
__global__ __launch_bounds__(256) void radon_kernel(const float* __restrict__ img,
                                                    const float* __restrict__ imgT,
                                                    float* __restrict__ out) {
    const int gid = blockIdx.x * 256 + threadIdx.x;
    const int o = gid >> 1;
    const int p = gid & 1;
    if (o >= TOTAL) return;

    const int t  = o % SPAD;
    const int ba = o / SPAD;
    const int a  = ba % N_ANGLES;
    const int b  = ba / N_ANGLES;

    const float theta = (float)a * 0.017453292519943295f;
    float s, c;
    sincosf(theta, &s, &c);

    const float d  = 2.0f / 362.0f;
    const float lt = fmaf((float)t, d, -1.0f);
    const float ct  = c * lt;
    const float mst = -s * lt;

    const bool useT = HAVE_T && (s > fabsf(c));
    const float sA = useT ? c   : s;
    const float cA = useT ? mst : ct;
    const float sB = useT ? s   : c;
    const float cB = useT ? ct  : mst;
    const float* __restrict__ base = (useT ? imgT : img) + b * (IMG * IMG);

    const float fA = sA * 181.0f;
    const float gA = (cA + 1.0f) * 181.0f;
    const float fB = sB * 181.0f;
    const float gB = (cB + 1.0f) * 181.0f;

    const float v0A = fmaf(fA, -1.0f, gA), dvA = fA * d;
    const float v0B = fmaf(fB, -1.0f, gB), dvB = fB * d;

    auto clip = [](float v0, float dv, float lo, float hi, float& rlo, float& rhi) {
        if (fabsf(dv) < 1e-5f) {
            if (v0 < lo || v0 > hi) { rlo = 363.0f; rhi = -1.0f; }
        } else {
            const float r0 = (lo - v0) / dv;
            const float r1 = (hi - v0) / dv;
            rlo = fmaxf(rlo, fminf(r0, r1));
            rhi = fminf(rhi, fmaxf(r0, r1));
        }
    };

    float rloA = 0.0f, rhiA = 362.0f;
    clip(v0A, dvA, 51.0f, 310.0f, rloA, rhiA);
    clip(v0B, dvB, 51.0f, 310.0f, rloA, rhiA);
    const int rmin = max(0,   (int)floorf(rloA));
    const int rmax = min(362, (int)ceilf(rhiA));

    float rloI = (float)rmin, rhiI = (float)rmax;
    clip(v0A, dvA, 54.0f, 307.0f, rloI, rhiI);
    clip(v0B, dvB, 54.0f, 307.0f, rloI, rhiI);
    int rin_lo = (int)ceilf(rloI);
    int rin_hi = (int)floorf(rhiI);
    if (rin_lo < rmin) rin_lo = rmin;
    if (rin_hi > rmax) rin_hi = rmax;
    if (rin_lo > rin_hi) { rin_lo = rmax + 1; rin_hi = rmax; }

    float acc = 0.0f;
    for (int r = rmin + ((p - rmin) & 1); r < rin_lo; r += 2)
        SAMPLE(r, true);
#pragma unroll 2
    for (int r = rin_lo + ((p - rin_lo) & 1); r <= rin_hi; r += 2)
        SAMPLE(r, false);
    for (int r = rin_hi + 1 + ((p - rin_hi - 1) & 1); r <= rmax; r += 2)
        SAMPLE(r, true);

    acc += __shfl_xor(acc, 1);

    if (p == 0) {
        out[(b * SPAD + t) * N_ANGLES + a] = acc;
    }
}

extern "C" void kernel_launch(void* const* d_in, const int* in_sizes, int n_in,
                              void* d_out, int out_size, void* d_ws, size_t ws_size,
                              hipStream_t stream) {
    const float* img = (const float*)d_in[0];
    float* out = (float*)d_out;

    const size_t needQ = (size_t)(2 * QELEMS) * 2 * sizeof(float4);   // ~4.6 MB
    if (ws_size >= needQ) {
        float4* quad = (float4*)d_ws;
        prep_quad2<<<(2 * QELEMS + 255) / 256, 256, 0, stream>>>(img, quad);
        radon_quad2<<<NPAD, 256, 0, stream>>>(quad, out);
    } else if (ws_size >= (size_t)(BATCH * IMG * IMG * sizeof(float))) {
        float* imgT = (float*)d_ws;
        transpose_kernel<<<dim3(8, 8, 2), 256, 0, stream>>>(img, imgT);
        const int threads = TOTAL * 2;
        radon_kernel<true><<<(threads + 255) / 256, 256, 0, stream>>>(img, imgT, out);
    } else {
        const int threads = TOTAL * 2;
        radon_kernel<false><<<(threads + 255) / 256, 256, 0, stream>>>(img, nullptr, out);
    }
}